// Round 5
// baseline (361.861 us; speedup 1.0000x reference)
//
#include <hip/hip_runtime.h>
#include <hip/hip_cooperative_groups.h>
#include <stdint.h>

namespace cg = cooperative_groups;

// ---------------- workspace layout ----------------
// [0, 1572864)        : syn  u32[3][4096][32]  packed synapses: col(12b) | sign<<31
// [2097152, 2621440)  : bits_x  u64[16][4096]  transposed activation bits (bit = b&63)
// [2621440, 3145728)  : bits_a0
// [3145728, 3670016)  : bits_a1
// [3670016, 4194304)  : bits_a2

// Fused prep: blocks [0,3072) sparsify the weights (one wave per row, loads
// hoisted 8-deep for MLP); blocks [3072,3328) pack x into transposed bitmasks.
__global__ __launch_bounds__(256) void prep_kernel(const float* __restrict__ x,
                                                   const float* __restrict__ w0,
                                                   const float* __restrict__ w1,
                                                   const float* __restrict__ w2,
                                                   uint32_t* __restrict__ syn,
                                                   uint64_t* __restrict__ bits) {
    const int blk = blockIdx.x;
    const int tid = threadIdx.x;
    if (blk < 3072) {
        // ---- sparsify: one wave per weight row, ballot-prefix slot assignment ----
        const int wid   = blk * 4 + (tid >> 6);  // row 0..12287
        const int lane  = tid & 63;
        const int layer = wid >> 12;
        const int r     = wid & 4095;
        const float* wp = (layer == 0 ? w0 : (layer == 1 ? w1 : w2)) + (size_t)r * 4096;
        const float4* wp4 = (const float4*)wp;
        uint32_t* srow  = syn + (size_t)wid * 32;
        const uint64_t lt = (1ull << lane) - 1ull;
        uint32_t base = 0;
#pragma unroll
        for (int half = 0; half < 2; ++half) {
            float4 v[8];
#pragma unroll
            for (int it = 0; it < 8; ++it)
                v[it] = wp4[half * 512 + it * 64 + lane];   // 8 loads in flight
#pragma unroll
            for (int it = 0; it < 8; ++it) {
                const int col = half * 2048 + it * 256 + lane * 4;
                const float4 q = v[it];
                const uint64_t m0 = __ballot(q.x != 0.0f);
                const uint64_t m1 = __ballot(q.y != 0.0f);
                const uint64_t m2 = __ballot(q.z != 0.0f);
                const uint64_t m3 = __ballot(q.w != 0.0f);
                const uint32_t t0 = (uint32_t)__popcll(m0), t1 = (uint32_t)__popcll(m1);
                const uint32_t t2 = (uint32_t)__popcll(m2), t3 = (uint32_t)__popcll(m3);
                if (q.x != 0.0f) { const uint32_t s = base + (uint32_t)__popcll(m0 & lt);
                    if (s < 32u) srow[s] = (uint32_t)col | (q.x < 0.0f ? 0x80000000u : 0u); }
                if (q.y != 0.0f) { const uint32_t s = base + t0 + (uint32_t)__popcll(m1 & lt);
                    if (s < 32u) srow[s] = (uint32_t)(col + 1) | (q.y < 0.0f ? 0x80000000u : 0u); }
                if (q.z != 0.0f) { const uint32_t s = base + t0 + t1 + (uint32_t)__popcll(m2 & lt);
                    if (s < 32u) srow[s] = (uint32_t)(col + 2) | (q.z < 0.0f ? 0x80000000u : 0u); }
                if (q.w != 0.0f) { const uint32_t s = base + t0 + t1 + t2 + (uint32_t)__popcll(m3 & lt);
                    if (s < 32u) srow[s] = (uint32_t)(col + 3) | (q.w < 0.0f ? 0x80000000u : 0u); }
                base += t0 + t1 + t2 + t3;
            }
        }
    } else {
        // ---- pack: thread owns one column, streams 64 rows, builds a u64 ----
        const int blk2 = blk - 3072;             // [0,256)
        const int bg   = blk2 >> 4;              // [0,16)
        const int c    = (blk2 & 15) * 256 + tid;
        const float* xp = x + (size_t)bg * 64 * 4096 + c;
        uint64_t acc = 0;
#pragma unroll
        for (int rr = 0; rr < 64; ++rr) {
            const float v = xp[(size_t)rr * 4096];
            acc |= (uint64_t)(v > 0.5f) << rr;
        }
        bits[(size_t)bg * 4096 + c] = acc;
    }
}

// Fused network: 3 bit-sliced layers with grid-wide sync between them, then the
// output einsum. Grid 256 x 256 thr (1 block/CU -> co-resident for cooperative).
// Block blk: bg = blk>>4 (batch group of 64), hblk = blk&15 (256-neuron chunk).
__global__ __launch_bounds__(256) void net_kernel(const uint64_t* __restrict__ bitsx,
                                                  const uint32_t* __restrict__ syn,
                                                  uint64_t* __restrict__ bits,
                                                  const float* __restrict__ oc,
                                                  float* __restrict__ out) {
    __shared__ uint64_t lb[4096];  // input bit-slice for this bg, 32 KB
    __shared__ float red[4][10];
    const int tid  = threadIdx.x;
    const int blk  = blockIdx.x;
    const int bg   = blk >> 4;
    const int hblk = blk & 15;
    cg::grid_group grid = cg::this_grid();

    for (int l = 0; l < 3; ++l) {
        const uint64_t* in = (l == 0) ? bitsx : (bits + (size_t)(l - 1) * 65536);
        const uint64_t* src = in + (size_t)bg * 4096;
#pragma unroll
        for (int i = 0; i < 8; ++i)
            ((uint4*)lb)[i * 256 + tid] = ((const uint4*)src)[i * 256 + tid];
        __syncthreads();

        const int h = hblk * 256 + tid;
        const uint32_t* srow = syn + (size_t)l * 131072 + (size_t)h * 32;
        uint32_t sw[32];
#pragma unroll
        for (int k = 0; k < 8; ++k)
            *(uint4*)(sw + k * 4) = *(const uint4*)(srow + k * 4);

        uint32_t thr = 16;
#pragma unroll
        for (int k = 0; k < 32; ++k) thr += sw[k] >> 31;

        // two independent 5-plane carry-save counters (16 synapses each) for ILP
        uint64_t a0 = 0, a1 = 0, a2 = 0, a3 = 0, a4 = 0;
        uint64_t b0 = 0, b1 = 0, b2 = 0, b3 = 0, b4 = 0;
#pragma unroll
        for (int k = 0; k < 32; k += 2) {
            {
                const uint32_t s = sw[k];
                uint64_t c = lb[s & 4095] ^ (uint64_t)(int64_t)((int32_t)s >> 31);
                uint64_t t;
                t = a0 & c; a0 ^= c; c = t;
                t = a1 & c; a1 ^= c; c = t;
                t = a2 & c; a2 ^= c; c = t;
                t = a3 & c; a3 ^= c; c = t;
                a4 ^= c;
            }
            {
                const uint32_t s = sw[k + 1];
                uint64_t c = lb[s & 4095] ^ (uint64_t)(int64_t)((int32_t)s >> 31);
                uint64_t t;
                t = b0 & c; b0 ^= c; c = t;
                t = b1 & c; b1 ^= c; c = t;
                t = b2 & c; b2 ^= c; c = t;
                t = b3 & c; b3 ^= c; c = t;
                b4 ^= c;
            }
        }
        // v = A + B, bitwise ripple-carry across planes
        uint64_t c;
        const uint64_t v0 = a0 ^ b0;     c = a0 & b0;
        const uint64_t v1 = a1 ^ b1 ^ c; c = (a1 & b1) | (c & (a1 ^ b1));
        const uint64_t v2 = a2 ^ b2 ^ c; c = (a2 & b2) | (c & (a2 ^ b2));
        const uint64_t v3 = a3 ^ b3 ^ c; c = (a3 & b3) | (c & (a3 ^ b3));
        const uint64_t v4 = a4 ^ b4 ^ c; c = (a4 & b4) | (c & (a4 ^ b4));
        const uint64_t v5 = c;
        // bitwise (v >= thr), MSB-first compare across the 64 batch positions
        uint64_t gt = 0, eq = ~0ull;
        {
            uint64_t tb;
            tb = ((thr >> 5) & 1u) ? ~0ull : 0ull; gt |= eq & v5 & ~tb; eq &= ~(v5 ^ tb);
            tb = ((thr >> 4) & 1u) ? ~0ull : 0ull; gt |= eq & v4 & ~tb; eq &= ~(v4 ^ tb);
            tb = ((thr >> 3) & 1u) ? ~0ull : 0ull; gt |= eq & v3 & ~tb; eq &= ~(v3 ^ tb);
            tb = ((thr >> 2) & 1u) ? ~0ull : 0ull; gt |= eq & v2 & ~tb; eq &= ~(v2 ^ tb);
            tb = ((thr >> 1) & 1u) ? ~0ull : 0ull; gt |= eq & v1 & ~tb; eq &= ~(v1 ^ tb);
            tb = ((thr >> 0) & 1u) ? ~0ull : 0ull; gt |= eq & v0 & ~tb; eq &= ~(v0 ^ tb);
        }
        (bits + (size_t)l * 65536)[(size_t)bg * 4096 + h] = gt | eq;
        grid.sync();
    }

    // ---- output einsum: each block handles 4 batch rows ----
    for (int rep = 0; rep < 4; ++rep) {
        const int b   = rep * 256 + blk;
        const int obg = b >> 6;
        const int sh  = b & 63;
        float acc[10];
#pragma unroll
        for (int cc = 0; cc < 10; ++cc) acc[cc] = 0.0f;
#pragma unroll
        for (int l = 0; l < 3; ++l) {
            const uint64_t* base = bits + (size_t)l * 65536 + (size_t)obg * 4096;
            const float* ocl = oc + (size_t)l * 40960;
#pragma unroll
            for (int i = 0; i < 16; ++i) {
                const int h = i * 256 + tid;
                if ((base[h] >> sh) & 1ull) {
                    const float* o = ocl + (size_t)h * 10;
#pragma unroll
                    for (int cc = 0; cc < 10; ++cc) acc[cc] += o[cc];
                }
            }
        }
#pragma unroll
        for (int cc = 0; cc < 10; ++cc) {
#pragma unroll
            for (int off = 32; off > 0; off >>= 1) acc[cc] += __shfl_down(acc[cc], off);
        }
        const int wave = tid >> 6;
        if ((tid & 63) == 0) {
#pragma unroll
            for (int cc = 0; cc < 10; ++cc) red[wave][cc] = acc[cc];
        }
        __syncthreads();
        if (tid < 10)
            out[(size_t)b * 10 + tid] = red[0][tid] + red[1][tid] + red[2][tid] + red[3][tid];
        __syncthreads();
    }
}

extern "C" void kernel_launch(void* const* d_in, const int* in_sizes, int n_in,
                              void* d_out, int out_size, void* d_ws, size_t ws_size,
                              hipStream_t stream) {
    const float* x  = (const float*)d_in[0];
    const float* w0 = (const float*)d_in[1];
    const float* w1 = (const float*)d_in[2];
    const float* w2 = (const float*)d_in[3];
    const float* oc = (const float*)d_in[4];
    float* out = (float*)d_out;

    uint32_t* syn   = (uint32_t*)d_ws;
    uint64_t* bitsx = (uint64_t*)((char*)d_ws + 2097152);
    uint64_t* bits0 = bitsx + 65536;

    prep_kernel<<<3328, 256, 0, stream>>>(x, w0, w1, w2, syn, bitsx);

    const uint64_t* bitsx_c = bitsx;
    const uint32_t* syn_c   = syn;
    void* args[] = {(void*)&bitsx_c, (void*)&syn_c, (void*)&bits0, (void*)&oc, (void*)&out};
    hipLaunchCooperativeKernel((const void*)net_kernel, dim3(256), dim3(256),
                               args, 0, stream);
}

// Round 9
// 250.268 us; speedup vs baseline: 1.4459x; 1.4459x over previous
//
#include <hip/hip_runtime.h>
#include <stdint.h>

// ---------------- workspace layout ----------------
// [0, 1572864)        : syn  u32[3][4096][32]  (dead after layer 3; reused below)
// [0, 1966080)        : partial f32[16][48][640]  (out stage A, written after layers)
// [2097152, 2621440)  : bits_x  u64[16][4096]
// [2621440, 3145728)  : bits_a0
// [3145728, 3670016)  : bits_a1
// [3670016, 4194304)  : bits_a2

// Sparsify: one wave per weight row, ballot-prefix slot assignment.
// Loads hoisted 4-deep per group for memory-level parallelism.
__global__ __launch_bounds__(256) void sparsify_kernel(const float* __restrict__ w0,
                                                       const float* __restrict__ w1,
                                                       const float* __restrict__ w2,
                                                       uint32_t* __restrict__ syn) {
    const int wid   = blockIdx.x * 4 + (threadIdx.x >> 6);  // row 0..12287
    const int lane  = threadIdx.x & 63;
    const int layer = wid >> 12;
    const int r     = wid & 4095;
    const float* wp = (layer == 0 ? w0 : (layer == 1 ? w1 : w2)) + (size_t)r * 4096;
    const float4* wp4 = (const float4*)wp;
    uint32_t* srow  = syn + (size_t)wid * 32;
    const uint64_t lt = (1ull << lane) - 1ull;
    uint32_t base = 0;
    for (int grp = 0; grp < 4; ++grp) {
        float4 v[4];
#pragma unroll
        for (int it = 0; it < 4; ++it)
            v[it] = wp4[grp * 256 + it * 64 + lane];   // 4 loads in flight
#pragma unroll
        for (int it = 0; it < 4; ++it) {
            const int col = grp * 1024 + it * 256 + lane * 4;
            const float4 q = v[it];
            const uint64_t m0 = __ballot(q.x != 0.0f);
            const uint64_t m1 = __ballot(q.y != 0.0f);
            const uint64_t m2 = __ballot(q.z != 0.0f);
            const uint64_t m3 = __ballot(q.w != 0.0f);
            const uint32_t t0 = (uint32_t)__popcll(m0), t1 = (uint32_t)__popcll(m1);
            const uint32_t t2 = (uint32_t)__popcll(m2), t3 = (uint32_t)__popcll(m3);
            if (q.x != 0.0f) { const uint32_t s = base + (uint32_t)__popcll(m0 & lt);
                if (s < 32u) srow[s] = (uint32_t)col | (q.x < 0.0f ? 0x80000000u : 0u); }
            if (q.y != 0.0f) { const uint32_t s = base + t0 + (uint32_t)__popcll(m1 & lt);
                if (s < 32u) srow[s] = (uint32_t)(col + 1) | (q.y < 0.0f ? 0x80000000u : 0u); }
            if (q.z != 0.0f) { const uint32_t s = base + t0 + t1 + (uint32_t)__popcll(m2 & lt);
                if (s < 32u) srow[s] = (uint32_t)(col + 2) | (q.z < 0.0f ? 0x80000000u : 0u); }
            if (q.w != 0.0f) { const uint32_t s = base + t0 + t1 + t2 + (uint32_t)__popcll(m3 & lt);
                if (s < 32u) srow[s] = (uint32_t)(col + 3) | (q.w < 0.0f ? 0x80000000u : 0u); }
            base += t0 + t1 + t2 + t3;
        }
    }
}

// Pack x[1024][4096] -> transposed bitmasks (thread owns a column, coalesced across lanes).
__global__ __launch_bounds__(256) void pack_kernel(const float* __restrict__ x,
                                                   uint64_t* __restrict__ bits) {
    const int c  = blockIdx.x * 256 + threadIdx.x;  // 0..4095
    const int bg = blockIdx.y;                      // 0..15
    const float* xp = x + (size_t)bg * 64 * 4096 + c;
    uint64_t acc = 0;
#pragma unroll
    for (int r = 0; r < 64; ++r) {
        const float v = xp[(size_t)r * 4096];
        acc |= (uint64_t)(v > 0.5f) << r;
    }
    bits[(size_t)bg * 4096 + c] = acc;
}

// Bit-sliced layer: thread computes all 64 batch-bits of ONE neuron via
// carry-save bitplane counters over u64 input-bit masks. (verified rounds 1/2/5)
__global__ __launch_bounds__(256) void layer_kernel(const uint64_t* __restrict__ in_bits,
                                                    const uint32_t* __restrict__ syn,
                                                    uint64_t* __restrict__ out_bits) {
    __shared__ uint64_t lb[4096];  // this bg's input bit-slice, 32 KB
    const int tid = threadIdx.x;
    const int bg  = blockIdx.y;
    const uint64_t* src = in_bits + (size_t)bg * 4096;
#pragma unroll
    for (int i = 0; i < 8; ++i)
        ((uint4*)lb)[i * 256 + tid] = ((const uint4*)src)[i * 256 + tid];
    __syncthreads();

    const int h = blockIdx.x * 256 + tid;
    const uint32_t* srow = syn + (size_t)h * 32;
    uint32_t sw[32];
#pragma unroll
    for (int k = 0; k < 8; ++k)
        *(uint4*)(sw + k * 4) = *(const uint4*)(srow + k * 4);

    uint32_t thr = 16;
#pragma unroll
    for (int k = 0; k < 32; ++k) thr += sw[k] >> 31;

    uint64_t a0 = 0, a1 = 0, a2 = 0, a3 = 0, a4 = 0;
    uint64_t b0 = 0, b1 = 0, b2 = 0, b3 = 0, b4 = 0;
#pragma unroll
    for (int k = 0; k < 32; k += 2) {
        {
            const uint32_t s = sw[k];
            uint64_t c = lb[s & 4095] ^ (uint64_t)(int64_t)((int32_t)s >> 31);
            uint64_t t;
            t = a0 & c; a0 ^= c; c = t;
            t = a1 & c; a1 ^= c; c = t;
            t = a2 & c; a2 ^= c; c = t;
            t = a3 & c; a3 ^= c; c = t;
            a4 ^= c;
        }
        {
            const uint32_t s = sw[k + 1];
            uint64_t c = lb[s & 4095] ^ (uint64_t)(int64_t)((int32_t)s >> 31);
            uint64_t t;
            t = b0 & c; b0 ^= c; c = t;
            t = b1 & c; b1 ^= c; c = t;
            t = b2 & c; b2 ^= c; c = t;
            t = b3 & c; b3 ^= c; c = t;
            b4 ^= c;
        }
    }
    uint64_t c;
    const uint64_t v0 = a0 ^ b0;     c = a0 & b0;
    const uint64_t v1 = a1 ^ b1 ^ c; c = (a1 & b1) | (c & (a1 ^ b1));
    const uint64_t v2 = a2 ^ b2 ^ c; c = (a2 & b2) | (c & (a2 ^ b2));
    const uint64_t v3 = a3 ^ b3 ^ c; c = (a3 & b3) | (c & (a3 ^ b3));
    const uint64_t v4 = a4 ^ b4 ^ c; c = (a4 & b4) | (c & (a4 ^ b4));
    const uint64_t v5 = c;
    uint64_t gt = 0, eq = ~0ull;
    {
        uint64_t tb;
        tb = ((thr >> 5) & 1u) ? ~0ull : 0ull; gt |= eq & v5 & ~tb; eq &= ~(v5 ^ tb);
        tb = ((thr >> 4) & 1u) ? ~0ull : 0ull; gt |= eq & v4 & ~tb; eq &= ~(v4 ^ tb);
        tb = ((thr >> 3) & 1u) ? ~0ull : 0ull; gt |= eq & v3 & ~tb; eq &= ~(v3 ^ tb);
        tb = ((thr >> 2) & 1u) ? ~0ull : 0ull; gt |= eq & v2 & ~tb; eq &= ~(v2 ^ tb);
        tb = ((thr >> 1) & 1u) ? ~0ull : 0ull; gt |= eq & v1 & ~tb; eq &= ~(v1 ^ tb);
        tb = ((thr >> 0) & 1u) ? ~0ull : 0ull; gt |= eq & v0 & ~tb; eq &= ~(v0 ^ tb);
    }
    out_bits[(size_t)bg * 4096 + h] = gt | eq;
}

// Out stage A: lane = batch row within bg; per hidden row: wave-uniform bits word +
// broadcast 10-float oc row, gated fmacs. Each wave owns 64 rows of the 256-row
// chunk; waves combine via LDS (fixes round-6 write race), block writes one
// 640-float partial per (bg, chunk).
__global__ __launch_bounds__(256) void outA_kernel(const uint64_t* __restrict__ bits,
                                                   const float* __restrict__ oc,
                                                   float* __restrict__ partial) {
    __shared__ float red[4][640];
    const int tid   = threadIdx.x;
    const int chunk = blockIdx.x;   // 0..47 (rows of [3][4096] flattened, 256 per chunk)
    const int bg    = blockIdx.y;   // 0..15
    const int wave  = tid >> 6;
    const int lane  = tid & 63;
    const int r0 = chunk * 256 + wave * 64;      // 64 rows, never straddles a layer
    const int l  = r0 >> 12;
    const int h0 = r0 & 4095;
    const uint64_t* bw = bits + (size_t)l * 65536 + (size_t)bg * 4096 + h0;
    const float* op = oc + (size_t)r0 * 10;

    float acc[10];
#pragma unroll
    for (int cc = 0; cc < 10; ++cc) acc[cc] = 0.0f;

#pragma unroll 4
    for (int i = 0; i < 64; ++i) {
        const uint64_t w = bw[i];
        const float bitf = (float)((w >> lane) & 1ull);
        const float2* o2 = (const float2*)(op + (size_t)i * 10);
        const float2 p0 = o2[0], p1 = o2[1], p2 = o2[2], p3 = o2[3], p4 = o2[4];
        acc[0] += bitf * p0.x; acc[1] += bitf * p0.y;
        acc[2] += bitf * p1.x; acc[3] += bitf * p1.y;
        acc[4] += bitf * p2.x; acc[5] += bitf * p2.y;
        acc[6] += bitf * p3.x; acc[7] += bitf * p3.y;
        acc[8] += bitf * p4.x; acc[9] += bitf * p4.y;
    }
#pragma unroll
    for (int cc = 0; cc < 10; ++cc) red[wave][lane * 10 + cc] = acc[cc];
    __syncthreads();

    float* dst = partial + ((size_t)bg * 48 + chunk) * 640;
    for (int idx = tid; idx < 640; idx += 256)
        dst[idx] = red[0][idx] + red[1][idx] + red[2][idx] + red[3][idx];
}

// Out stage B: deterministic reduce over the 48 chunks. out flat index g = b*10+c.
__global__ __launch_bounds__(256) void outB_kernel(const float* __restrict__ partial,
                                                   float* __restrict__ out) {
    const int g  = blockIdx.x * 256 + threadIdx.x;   // 0..10239
    const int bg = g / 640;
    const int s  = g - bg * 640;
    const float* p = partial + (size_t)bg * 48 * 640 + s;
    float sum = 0.0f;
#pragma unroll
    for (int ch = 0; ch < 48; ++ch) sum += p[ch * 640];
    out[g] = sum;
}

extern "C" void kernel_launch(void* const* d_in, const int* in_sizes, int n_in,
                              void* d_out, int out_size, void* d_ws, size_t ws_size,
                              hipStream_t stream) {
    const float* x  = (const float*)d_in[0];
    const float* w0 = (const float*)d_in[1];
    const float* w1 = (const float*)d_in[2];
    const float* w2 = (const float*)d_in[3];
    const float* oc = (const float*)d_in[4];
    float* out = (float*)d_out;

    uint32_t* syn    = (uint32_t*)d_ws;
    float*    part   = (float*)d_ws;     // overlays syn AFTER the layers are done
    uint64_t* bitsx  = (uint64_t*)((char*)d_ws + 2097152);
    uint64_t* bits0  = bitsx + 65536;
    uint64_t* bits1  = bits0 + 65536;
    uint64_t* bits2  = bits1 + 65536;

    sparsify_kernel<<<3072, 256, 0, stream>>>(w0, w1, w2, syn);
    pack_kernel<<<dim3(16, 16), 256, 0, stream>>>(x, bitsx);

    layer_kernel<<<dim3(16, 16), 256, 0, stream>>>(bitsx, syn,          bits0);
    layer_kernel<<<dim3(16, 16), 256, 0, stream>>>(bits0, syn + 131072, bits1);
    layer_kernel<<<dim3(16, 16), 256, 0, stream>>>(bits1, syn + 262144, bits2);

    outA_kernel<<<dim3(48, 16), 256, 0, stream>>>(bits0, oc, part);
    outB_kernel<<<40, 256, 0, stream>>>(part, out);
}

// Round 10
// 237.546 us; speedup vs baseline: 1.5233x; 1.0536x over previous
//
#include <hip/hip_runtime.h>
#include <stdint.h>

#define AS1 __attribute__((address_space(1)))
#define AS3 __attribute__((address_space(3)))

// ---------------- workspace layout ----------------
// [0, 1572864)        : syn  u32[3][4096][32]  (dead after layer 3; reused below)
// [0, 1966080)        : partial f32[16][48][640]  (out stage A, written after layers)
// [2097152, 2621440)  : bits_x  u64[16][4096]
// [2621440, 3145728)  : bits_a0
// [3145728, 3670016)  : bits_a1
// [3670016, 4194304)  : bits_a2

// Fused prep. Blocks [0,12288): sparsify one weight row per block — stage the
// 16 KB row into LDS via global_load_lds (16 loads in flight, no VGPR consumer
// -> no per-load vmcnt serialization), then ballot-compact per wave-quarter
// with a cross-wave LDS count/offset exchange.
// Blocks [12288,12544): pack x into transposed bitmasks, float4-wide.
__global__ __launch_bounds__(256) void prep_kernel(const float* __restrict__ x,
                                                   const float* __restrict__ w0,
                                                   const float* __restrict__ w1,
                                                   const float* __restrict__ w2,
                                                   uint32_t* __restrict__ syn,
                                                   uint64_t* __restrict__ bits) {
    __shared__ __align__(16) uint8_t smem[16448];
    const int blk  = blockIdx.x;
    const int tid  = threadIdx.x;
    const int wave = tid >> 6;
    const int lane = tid & 63;

    if (blk < 12288) {
        float*    lb   = (float*)smem;               // 16 KB row buffer
        uint32_t* wcnt = (uint32_t*)(smem + 16384);  // per-wave nonzero counts
        const int layer = blk >> 12;
        const int r     = blk & 4095;
        const float* wp = (layer == 0 ? w0 : (layer == 1 ? w1 : w2)) + (size_t)r * 4096;
        uint32_t* srow  = syn + (size_t)blk * 32;

        // ---- stage 16 KB row -> LDS: wave w covers chunks [w*4, w*4+4) ----
#pragma unroll
        for (int i = 0; i < 4; ++i) {
            const int c = wave * 4 + i;   // 1 KB chunk: floats [c*256, c*256+256)
            __builtin_amdgcn_global_load_lds(
                (const AS1 void*)(wp + c * 256 + lane * 4),
                (AS3 void*)(lb + c * 256), 16, 0, 0);
        }
        __syncthreads();

        // ---- phase A: read quarter, count nonzeros ----
        float4 q[4];
#pragma unroll
        for (int it = 0; it < 4; ++it)
            q[it] = ((const float4*)lb)[wave * 256 + it * 64 + lane];
        uint32_t cnt = 0;
#pragma unroll
        for (int it = 0; it < 4; ++it) {
            cnt += (uint32_t)__popcll(__ballot(q[it].x != 0.0f));
            cnt += (uint32_t)__popcll(__ballot(q[it].y != 0.0f));
            cnt += (uint32_t)__popcll(__ballot(q[it].z != 0.0f));
            cnt += (uint32_t)__popcll(__ballot(q[it].w != 0.0f));
        }
        if (lane == 0) wcnt[wave] = cnt;
        __syncthreads();
        uint32_t base = 0;
#pragma unroll
        for (int w2 = 0; w2 < 4; ++w2) base += (w2 < wave) ? wcnt[w2] : 0u;

        // ---- phase B: ballot-prefix slot assignment within the quarter ----
        const uint64_t lt = (1ull << lane) - 1ull;
#pragma unroll
        for (int it = 0; it < 4; ++it) {
            const int col = wave * 1024 + it * 256 + lane * 4;
            const float4 p = q[it];
            const uint64_t m0 = __ballot(p.x != 0.0f);
            const uint64_t m1 = __ballot(p.y != 0.0f);
            const uint64_t m2 = __ballot(p.z != 0.0f);
            const uint64_t m3 = __ballot(p.w != 0.0f);
            const uint32_t t0 = (uint32_t)__popcll(m0), t1 = (uint32_t)__popcll(m1);
            const uint32_t t2 = (uint32_t)__popcll(m2), t3 = (uint32_t)__popcll(m3);
            if (p.x != 0.0f) { const uint32_t s = base + (uint32_t)__popcll(m0 & lt);
                if (s < 32u) srow[s] = (uint32_t)col | (p.x < 0.0f ? 0x80000000u : 0u); }
            if (p.y != 0.0f) { const uint32_t s = base + t0 + (uint32_t)__popcll(m1 & lt);
                if (s < 32u) srow[s] = (uint32_t)(col + 1) | (p.y < 0.0f ? 0x80000000u : 0u); }
            if (p.z != 0.0f) { const uint32_t s = base + t0 + t1 + (uint32_t)__popcll(m2 & lt);
                if (s < 32u) srow[s] = (uint32_t)(col + 2) | (p.z < 0.0f ? 0x80000000u : 0u); }
            if (p.w != 0.0f) { const uint32_t s = base + t0 + t1 + t2 + (uint32_t)__popcll(m3 & lt);
                if (s < 32u) srow[s] = (uint32_t)(col + 3) | (p.w < 0.0f ? 0x80000000u : 0u); }
            base += t0 + t1 + t2 + t3;
        }
    } else {
        // ---- pack: block = (cchunk of 256 cols, bg). wave w handles 16 rows;
        // lane owns 4 consecutive columns (float4 loads, 1 KB/wave-instr). ----
        uint16_t* pk = (uint16_t*)smem;   // [4][256] per-wave 16-row bit partials
        const int blk2   = blk - 12288;   // [0,256)
        const int bg     = blk2 >> 4;
        const int cchunk = blk2 & 15;
        const float* xb = x + ((size_t)(bg * 64 + wave * 16)) * 4096 + cchunk * 256 + lane * 4;
        uint32_t b0 = 0, b1 = 0, b2 = 0, b3 = 0;
#pragma unroll
        for (int r = 0; r < 16; ++r) {
            const float4 p = *(const float4*)(xb + (size_t)r * 4096);
            b0 |= (uint32_t)(p.x > 0.5f) << r;
            b1 |= (uint32_t)(p.y > 0.5f) << r;
            b2 |= (uint32_t)(p.z > 0.5f) << r;
            b3 |= (uint32_t)(p.w > 0.5f) << r;
        }
        pk[wave * 256 + lane * 4 + 0] = (uint16_t)b0;
        pk[wave * 256 + lane * 4 + 1] = (uint16_t)b1;
        pk[wave * 256 + lane * 4 + 2] = (uint16_t)b2;
        pk[wave * 256 + lane * 4 + 3] = (uint16_t)b3;
        __syncthreads();
        const uint64_t vv = (uint64_t)pk[tid]
                          | ((uint64_t)pk[256 + tid] << 16)
                          | ((uint64_t)pk[512 + tid] << 32)
                          | ((uint64_t)pk[768 + tid] << 48);
        bits[(size_t)bg * 4096 + cchunk * 256 + tid] = vv;
    }
}

// Bit-sliced layer: thread computes all 64 batch-bits of ONE neuron via
// carry-save bitplane counters over u64 input-bit masks. (verified rounds 1/2/5/9)
__global__ __launch_bounds__(256) void layer_kernel(const uint64_t* __restrict__ in_bits,
                                                    const uint32_t* __restrict__ syn,
                                                    uint64_t* __restrict__ out_bits) {
    __shared__ uint64_t lb[4096];  // this bg's input bit-slice, 32 KB
    const int tid = threadIdx.x;
    const int bg  = blockIdx.y;
    const uint64_t* src = in_bits + (size_t)bg * 4096;
#pragma unroll
    for (int i = 0; i < 8; ++i)
        ((uint4*)lb)[i * 256 + tid] = ((const uint4*)src)[i * 256 + tid];
    __syncthreads();

    const int h = blockIdx.x * 256 + tid;
    const uint32_t* srow = syn + (size_t)h * 32;
    uint32_t sw[32];
#pragma unroll
    for (int k = 0; k < 8; ++k)
        *(uint4*)(sw + k * 4) = *(const uint4*)(srow + k * 4);

    uint32_t thr = 16;
#pragma unroll
    for (int k = 0; k < 32; ++k) thr += sw[k] >> 31;

    uint64_t a0 = 0, a1 = 0, a2 = 0, a3 = 0, a4 = 0;
    uint64_t b0 = 0, b1 = 0, b2 = 0, b3 = 0, b4 = 0;
#pragma unroll
    for (int k = 0; k < 32; k += 2) {
        {
            const uint32_t s = sw[k];
            uint64_t c = lb[s & 4095] ^ (uint64_t)(int64_t)((int32_t)s >> 31);
            uint64_t t;
            t = a0 & c; a0 ^= c; c = t;
            t = a1 & c; a1 ^= c; c = t;
            t = a2 & c; a2 ^= c; c = t;
            t = a3 & c; a3 ^= c; c = t;
            a4 ^= c;
        }
        {
            const uint32_t s = sw[k + 1];
            uint64_t c = lb[s & 4095] ^ (uint64_t)(int64_t)((int32_t)s >> 31);
            uint64_t t;
            t = b0 & c; b0 ^= c; c = t;
            t = b1 & c; b1 ^= c; c = t;
            t = b2 & c; b2 ^= c; c = t;
            t = b3 & c; b3 ^= c; c = t;
            b4 ^= c;
        }
    }
    uint64_t c;
    const uint64_t v0 = a0 ^ b0;     c = a0 & b0;
    const uint64_t v1 = a1 ^ b1 ^ c; c = (a1 & b1) | (c & (a1 ^ b1));
    const uint64_t v2 = a2 ^ b2 ^ c; c = (a2 & b2) | (c & (a2 ^ b2));
    const uint64_t v3 = a3 ^ b3 ^ c; c = (a3 & b3) | (c & (a3 ^ b3));
    const uint64_t v4 = a4 ^ b4 ^ c; c = (a4 & b4) | (c & (a4 ^ b4));
    const uint64_t v5 = c;
    uint64_t gt = 0, eq = ~0ull;
    {
        uint64_t tb;
        tb = ((thr >> 5) & 1u) ? ~0ull : 0ull; gt |= eq & v5 & ~tb; eq &= ~(v5 ^ tb);
        tb = ((thr >> 4) & 1u) ? ~0ull : 0ull; gt |= eq & v4 & ~tb; eq &= ~(v4 ^ tb);
        tb = ((thr >> 3) & 1u) ? ~0ull : 0ull; gt |= eq & v3 & ~tb; eq &= ~(v3 ^ tb);
        tb = ((thr >> 2) & 1u) ? ~0ull : 0ull; gt |= eq & v2 & ~tb; eq &= ~(v2 ^ tb);
        tb = ((thr >> 1) & 1u) ? ~0ull : 0ull; gt |= eq & v1 & ~tb; eq &= ~(v1 ^ tb);
        tb = ((thr >> 0) & 1u) ? ~0ull : 0ull; gt |= eq & v0 & ~tb; eq &= ~(v0 ^ tb);
    }
    out_bits[(size_t)bg * 4096 + h] = gt | eq;
}

// Out stage A: lane = batch row within bg; per hidden row: wave-uniform bits word +
// broadcast 10-float oc row, gated fmacs. Waves combine via LDS (race-free),
// block writes one 640-float partial per (bg, chunk). (verified round 9)
__global__ __launch_bounds__(256) void outA_kernel(const uint64_t* __restrict__ bits,
                                                   const float* __restrict__ oc,
                                                   float* __restrict__ partial) {
    __shared__ float red[4][640];
    const int tid   = threadIdx.x;
    const int chunk = blockIdx.x;   // 0..47
    const int bg    = blockIdx.y;   // 0..15
    const int wave  = tid >> 6;
    const int lane  = tid & 63;
    const int r0 = chunk * 256 + wave * 64;
    const int l  = r0 >> 12;
    const int h0 = r0 & 4095;
    const uint64_t* bw = bits + (size_t)l * 65536 + (size_t)bg * 4096 + h0;
    const float* op = oc + (size_t)r0 * 10;

    float acc[10];
#pragma unroll
    for (int cc = 0; cc < 10; ++cc) acc[cc] = 0.0f;

#pragma unroll 4
    for (int i = 0; i < 64; ++i) {
        const uint64_t w = bw[i];
        const float bitf = (float)((w >> lane) & 1ull);
        const float2* o2 = (const float2*)(op + (size_t)i * 10);
        const float2 p0 = o2[0], p1 = o2[1], p2 = o2[2], p3 = o2[3], p4 = o2[4];
        acc[0] += bitf * p0.x; acc[1] += bitf * p0.y;
        acc[2] += bitf * p1.x; acc[3] += bitf * p1.y;
        acc[4] += bitf * p2.x; acc[5] += bitf * p2.y;
        acc[6] += bitf * p3.x; acc[7] += bitf * p3.y;
        acc[8] += bitf * p4.x; acc[9] += bitf * p4.y;
    }
#pragma unroll
    for (int cc = 0; cc < 10; ++cc) red[wave][lane * 10 + cc] = acc[cc];
    __syncthreads();

    float* dst = partial + ((size_t)bg * 48 + chunk) * 640;
    for (int idx = tid; idx < 640; idx += 256)
        dst[idx] = red[0][idx] + red[1][idx] + red[2][idx] + red[3][idx];
}

// Out stage B: deterministic reduce over the 48 chunks.
__global__ __launch_bounds__(256) void outB_kernel(const float* __restrict__ partial,
                                                   float* __restrict__ out) {
    const int g  = blockIdx.x * 256 + threadIdx.x;   // 0..10239
    const int bg = g / 640;
    const int s  = g - bg * 640;
    const float* p = partial + (size_t)bg * 48 * 640 + s;
    float sum = 0.0f;
#pragma unroll
    for (int ch = 0; ch < 48; ++ch) sum += p[ch * 640];
    out[g] = sum;
}

extern "C" void kernel_launch(void* const* d_in, const int* in_sizes, int n_in,
                              void* d_out, int out_size, void* d_ws, size_t ws_size,
                              hipStream_t stream) {
    const float* x  = (const float*)d_in[0];
    const float* w0 = (const float*)d_in[1];
    const float* w1 = (const float*)d_in[2];
    const float* w2 = (const float*)d_in[3];
    const float* oc = (const float*)d_in[4];
    float* out = (float*)d_out;

    uint32_t* syn    = (uint32_t*)d_ws;
    float*    part   = (float*)d_ws;     // overlays syn AFTER the layers are done
    uint64_t* bitsx  = (uint64_t*)((char*)d_ws + 2097152);
    uint64_t* bits0  = bitsx + 65536;
    uint64_t* bits1  = bits0 + 65536;
    uint64_t* bits2  = bits1 + 65536;

    prep_kernel<<<12544, 256, 0, stream>>>(x, w0, w1, w2, syn, bitsx);

    layer_kernel<<<dim3(16, 16), 256, 0, stream>>>(bitsx, syn,          bits0);
    layer_kernel<<<dim3(16, 16), 256, 0, stream>>>(bits0, syn + 131072, bits1);
    layer_kernel<<<dim3(16, 16), 256, 0, stream>>>(bits1, syn + 262144, bits2);

    outA_kernel<<<dim3(48, 16), 256, 0, stream>>>(bits0, oc, part);
    outB_kernel<<<40, 256, 0, stream>>>(part, out);
}